// Round 2
// baseline (979.303 us; speedup 1.0000x reference)
//
#include <hip/hip_runtime.h>
#include <hip/hip_bf16.h>
#include <math.h>

// Problem constants (fixed by reference): B=2,T=2048 -> N=4096 tokens
#define N_TOK 4096
#define D_DIM 1024
#define H_DIM 4096
#define E_NUM 8
#define NSLOT (N_TOK * 2)  // total assignments = N*TOPK = 8192

typedef short bf16x8 __attribute__((ext_vector_type(8)));
typedef float f32x4 __attribute__((ext_vector_type(4)));

// ---------------- helpers ----------------

__device__ __forceinline__ unsigned short f2bf(float f) {
  unsigned int u = __float_as_uint(f);
  u += 0x7FFFu + ((u >> 16) & 1u);  // round-to-nearest-even
  return (unsigned short)(u >> 16);
}

// async global->LDS, 16B per lane. LDS dest is wave-uniform base + lane*16
// (m104: per-lane scatter impossible; hence the XOR *source* swizzle below).
__device__ __forceinline__ void gld_lds16(const void* g, void* l) {
  __builtin_amdgcn_global_load_lds(
      (__attribute__((address_space(1))) void*)(g),
      (__attribute__((address_space(3))) void*)(l), 16, 0, 0);
}

// ---------------- small kernels ----------------

__global__ void init_ctrl(int* p) { p[threadIdx.x] = 0; }

__global__ void cvt_f32_bf16(const float* __restrict__ src,
                             unsigned short* __restrict__ dst, int n4) {
  int i = blockIdx.x * blockDim.x + threadIdx.x;
  if (i >= n4) return;
  float4 v = ((const float4*)src)[i];
  ushort4 o;
  o.x = f2bf(v.x); o.y = f2bf(v.y); o.z = f2bf(v.z); o.w = f2bf(v.w);
  ((ushort4*)dst)[i] = o;
}

__global__ void zero_f32(float* __restrict__ p, int n4) {
  int i = blockIdx.x * blockDim.x + threadIdx.x;
  if (i < n4) ((float4*)p)[i] = make_float4(0.f, 0.f, 0.f, 0.f);
}

// ---------------- gating: atomic-free ----------------

__global__ void gating_kernel(const float* __restrict__ x,
                              const float* __restrict__ wg,
                              float* __restrict__ probs,   // [N_TOK][E]
                              int* __restrict__ eidx,
                              float* __restrict__ rw) {
  __shared__ float4 wg_lds[2048];  // 8*1024 floats = 32 KB
  const int t = threadIdx.x;
  const int lane = t & 63;
  const int wave = t >> 6;

#pragma unroll
  for (int j = 0; j < 8; ++j)
    wg_lds[t + 256 * j] = ((const float4*)wg)[t + 256 * j];
  __syncthreads();

#pragma unroll
  for (int j = 0; j < 4; ++j) {
    const int n = blockIdx.x * 16 + wave * 4 + j;
    const float4* xr = (const float4*)(x + (size_t)n * D_DIM);

    float acc[E_NUM];
#pragma unroll
    for (int e = 0; e < E_NUM; ++e) acc[e] = 0.f;

#pragma unroll
    for (int i = 0; i < 4; ++i) {
      float4 xv = xr[lane + 64 * i];
#pragma unroll
      for (int e = 0; e < E_NUM; ++e) {
        float4 wv = wg_lds[e * 256 + lane + 64 * i];
        acc[e] += xv.x * wv.x + xv.y * wv.y + xv.z * wv.z + xv.w * wv.w;
      }
    }
#pragma unroll
    for (int m = 1; m < 64; m <<= 1) {
#pragma unroll
      for (int e = 0; e < E_NUM; ++e) acc[e] += __shfl_xor(acc[e], m, 64);
    }

    float mx = acc[0];
#pragma unroll
    for (int e = 1; e < E_NUM; ++e) mx = fmaxf(mx, acc[e]);
    float p[E_NUM], s = 0.f;
#pragma unroll
    for (int e = 0; e < E_NUM; ++e) { p[e] = __expf(acc[e] - mx); s += p[e]; }
    float inv = 1.f / s;

    if (lane < E_NUM) probs[(size_t)n * E_NUM + lane] = p[lane] * inv;

    if (lane == 0) {
      int i1 = 0;
#pragma unroll
      for (int e = 1; e < E_NUM; ++e) if (p[e] > p[i1]) i1 = e;
      int i2 = (i1 == 0) ? 1 : 0;
#pragma unroll
      for (int e = 0; e < E_NUM; ++e)
        if (e != i1 && p[e] > p[i2]) i2 = e;
      float p1 = p[i1], p2 = p[i2];
      float wsum = 1.f / (p1 + p2);  // top-2 renormalize (softmax scale cancels)
      eidx[n] = i1 | (i2 << 8);
      rw[2 * n] = p1 * wsum;
      rw[2 * n + 1] = p2 * wsum;
    }
  }
}

// single block: sumP column-sums, expert histogram, offsets, balance loss
__global__ void reduce_route(const float* __restrict__ probs,
                             const int* __restrict__ eidx,
                             int* __restrict__ counts,
                             int* __restrict__ offsets,
                             float* __restrict__ loss) {
  const int t = threadIdx.x;
  float4 part = make_float4(0.f, 0.f, 0.f, 0.f);
  for (int j = 0; j < 32; ++j) {
    float4 v = ((const float4*)probs)[t + 256 * j];
    part.x += v.x; part.y += v.y; part.z += v.z; part.w += v.w;
  }
  int cnt[E_NUM];
#pragma unroll
  for (int e = 0; e < E_NUM; ++e) cnt[e] = 0;
  for (int j = 0; j < 16; ++j) {
    int pk = eidx[t + 256 * j];
    int e1 = pk & 255, e2 = pk >> 8;
#pragma unroll
    for (int e = 0; e < E_NUM; ++e) cnt[e] += (e1 == e) + (e2 == e);
  }

  __shared__ float redf[256 * E_NUM];
  __shared__ int redi[256 * E_NUM];
  const int eb = (t & 1) * 4;
#pragma unroll
  for (int e = 0; e < E_NUM; ++e) { redf[t * E_NUM + e] = 0.f; redi[t * E_NUM + e] = cnt[e]; }
  redf[t * E_NUM + eb + 0] = part.x;
  redf[t * E_NUM + eb + 1] = part.y;
  redf[t * E_NUM + eb + 2] = part.z;
  redf[t * E_NUM + eb + 3] = part.w;
  __syncthreads();
  for (int s = 128; s > 0; s >>= 1) {
    if (t < s) {
#pragma unroll
      for (int e = 0; e < E_NUM; ++e) {
        redf[t * E_NUM + e] += redf[(t + s) * E_NUM + e];
        redi[t * E_NUM + e] += redi[(t + s) * E_NUM + e];
      }
    }
    __syncthreads();
  }
  if (t == 0) {
    int o = 0;
    float L = 0.f;
    for (int e = 0; e < E_NUM; ++e) {
      int c = redi[e];
      counts[e] = c;
      offsets[e] = o;
      o += c;
      L += redf[e] * (float)c;
    }
    loss[0] = L * (float)E_NUM / ((float)N_TOK * (float)N_TOK);
  }
}

// two-phase scatter: LDS-local positions, one global atomic per expert/block
__global__ void scatter_kernel(const int* __restrict__ eidx, const float* __restrict__ rw,
                               const int* __restrict__ offsets, int* __restrict__ cursor,
                               int* __restrict__ tok_id, float* __restrict__ tok_w) {
  __shared__ int lcnt[E_NUM];
  __shared__ int lbase[E_NUM];
  const int t = threadIdx.x;
  const int n = blockIdx.x * 256 + t;
  if (t < E_NUM) lcnt[t] = 0;
  __syncthreads();
  int pk = eidx[n];
  int e1 = pk & 255, e2 = pk >> 8;
  int p1 = atomicAdd(&lcnt[e1], 1);
  int p2 = atomicAdd(&lcnt[e2], 1);
  __syncthreads();
  if (t < E_NUM) lbase[t] = atomicAdd(&cursor[t], lcnt[t]);
  __syncthreads();
  int d1 = offsets[e1] + lbase[e1] + p1;
  tok_id[d1] = n; tok_w[d1] = rw[2 * n];
  int d2 = offsets[e2] + lbase[e2] + p2;
  tok_id[d2] = n; tok_w[d2] = rw[2 * n + 1];
}

// ---------------- grouped GEMMs: 128x128 tile, BK=32, LDS ring-4 ----------
// Post-R1 diagnosis: staging was latency*depth-bound (~8KB in flight/CU ->
// ~7 TB/s aggregate supply ceiling). Fixes:
//  - ring-4 of 16KB K-tile buffers (64 KB LDS) -> stage issued 3 K-tiles
//    ahead; 2 resident blocks/CU -> 64-96 KB in flight per CU (8x depth).
//  - ONE raw s_barrier per K-tile phase; counted vmcnt(8) steady state
//    (stage unit = 4 loads/thread; 2 newest stages may stay in flight);
//    drain peeled into last 3 iterations (vmcnt 4/0).
//  - XCD-locality: blockIdx.x = mtile so all ntile-siblings sharing an
//    A-panel land on the same XCD (linear%8==mtile%8) -> A re-reads hit
//    that XCD's L2 instead of L3/HBM.
// LDS swizzle (rows are 32 bf16 = 64 B = 4 chunks of 16 B): LDS(row, chunk c)
// holds global chunk c ^ ((row>>1)&3); staging pre-swizzles the SOURCE
// address (dest stays linear for global_load_lds); frag readers use
// chunk = q ^ ((fr>>1)&3). Rows 8 apart alias -> 2-way only (free, m136).

#define BK 32
#define RING 4
#define BUFSZ 8192              // shorts per buffer: A 128x32 + B 128x32
#define SRC_CHUNK(s) ((((s) & 3) ^ (((s) >> 3) & 3)) * 8)

__launch_bounds__(256, 2)
__global__ void gemm_fc(const unsigned short* __restrict__ xb,    // [N_TOK][D]
                        const unsigned short* __restrict__ wfc,   // [E][H][D]
                        const int* __restrict__ tok_id,
                        const int* __restrict__ counts,
                        const int* __restrict__ offsets,
                        unsigned short* __restrict__ hbuf) {      // [NSLOT][H]
  const int e = blockIdx.z;
  const int cnt = counts[e];
  const int mtile = blockIdx.x;   // x = mtile: XCD = mtile%8 (A-panel L2 locality)
  if (mtile * 128 >= cnt) return;
  const int ntile = blockIdx.y;
  const int off = offsets[e];

  __shared__ __align__(16) unsigned short lds[RING * BUFSZ];  // 64 KB

  const int t = threadIdx.x;
  const int lane = t & 63;
  const int wave = t >> 6;
  const int wm = (wave >> 1) * 64;
  const int wn = (wave & 1) * 64;

  // staging source pointers: slots {t, t+256} for A and B
  const int s0 = t, s1 = t + 256;
  int r0 = mtile * 128 + (s0 >> 2); r0 = (r0 < cnt) ? r0 : (cnt - 1);
  int r1 = mtile * 128 + (s1 >> 2); r1 = (r1 < cnt) ? r1 : (cnt - 1);
  const unsigned short* ga0 = xb + (size_t)tok_id[off + r0] * D_DIM + SRC_CHUNK(s0);
  const unsigned short* ga1 = xb + (size_t)tok_id[off + r1] * D_DIM + SRC_CHUNK(s1);
  const unsigned short* gb0 = wfc + ((size_t)e * H_DIM + ntile * 128 + (s0 >> 2)) * D_DIM + SRC_CHUNK(s0);
  const unsigned short* gb1 = wfc + ((size_t)e * H_DIM + ntile * 128 + (s1 >> 2)) * D_DIM + SRC_CHUNK(s1);

  f32x4 acc[4][4];
#pragma unroll
  for (int i = 0; i < 4; ++i)
#pragma unroll
    for (int j = 0; j < 4; ++j) acc[i][j] = (f32x4){0.f, 0.f, 0.f, 0.f};

  const int fr = lane & 15;
  const int q = lane >> 4;
  const int ch = (q ^ ((fr >> 1) & 3)) * 8;   // swizzled chunk (shorts)

  const int NK = D_DIM / BK;  // 32

  // prologue: stage kt=0,1,2 into buffers 0,1,2
#pragma unroll
  for (int p = 0; p < 3; ++p) {
    gld_lds16(ga0 + p * BK, &lds[p * BUFSZ + t * 8]);
    gld_lds16(ga1 + p * BK, &lds[p * BUFSZ + 2048 + t * 8]);
    gld_lds16(gb0 + p * BK, &lds[p * BUFSZ + 4096 + t * 8]);
    gld_lds16(gb1 + p * BK, &lds[p * BUFSZ + 4096 + 2048 + t * 8]);
  }
  asm volatile("s_waitcnt vmcnt(8)" ::: "memory");
  __builtin_amdgcn_s_barrier();

  for (int kt = 0; kt < NK; ++kt) {
    const int bb = (kt & 3) * BUFSZ;
    const unsigned short* Ab = &lds[bb + (wm + fr) * 32 + ch];
    const unsigned short* Bb = &lds[bb + 4096 + (wn + fr) * 32 + ch];

    bf16x8 a_[4], b_[4];
#pragma unroll
    for (int i = 0; i < 4; ++i) a_[i] = *(const bf16x8*)(Ab + i * 512);
#pragma unroll
    for (int j = 0; j < 4; ++j) b_[j] = *(const bf16x8*)(Bb + j * 512);

    if (kt + 3 < NK) {
      const int kof = (kt + 3) * BK;
      const int sb = ((kt + 3) & 3) * BUFSZ;
      gld_lds16(ga0 + kof, &lds[sb + t * 8]);
      gld_lds16(ga1 + kof, &lds[sb + 2048 + t * 8]);
      gld_lds16(gb0 + kof, &lds[sb + 4096 + t * 8]);
      gld_lds16(gb1 + kof, &lds[sb + 4096 + 2048 + t * 8]);
    }

    __builtin_amdgcn_s_setprio(1);
#pragma unroll
    for (int i = 0; i < 4; ++i)
#pragma unroll
      for (int j = 0; j < 4; ++j)
        acc[i][j] = __builtin_amdgcn_mfma_f32_16x16x32_bf16(a_[i], b_[j], acc[i][j], 0, 0, 0);
    __builtin_amdgcn_s_setprio(0);

    if (kt < NK - 3)       asm volatile("s_waitcnt vmcnt(8)" ::: "memory");
    else if (kt == NK - 3) asm volatile("s_waitcnt vmcnt(4)" ::: "memory");
    else if (kt == NK - 2) asm volatile("s_waitcnt vmcnt(0)" ::: "memory");
    if (kt != NK - 1) __builtin_amdgcn_s_barrier();
  }

  // epilogue: h = relu(t)^2, cast bf16, store
  const int lm = (lane >> 4) * 4;
  const int ln = lane & 15;
#pragma unroll
  for (int i = 0; i < 4; ++i) {
#pragma unroll
    for (int r = 0; r < 4; ++r) {
      int m = mtile * 128 + wm + i * 16 + lm + r;
      if (m < cnt) {
        size_t rowbase = (size_t)(off + m) * H_DIM + ntile * 128 + wn;
#pragma unroll
        for (int j = 0; j < 4; ++j) {
          float v = acc[i][j][r];
          v = v > 0.f ? v * v : 0.f;
          hbuf[rowbase + j * 16 + ln] = f2bf(v);
        }
      }
    }
  }
}

// split-K=2: z = e*2 + khalf; both halves atomicAdd into zero-initialized out.
__launch_bounds__(256, 2)
__global__ void gemm_proj(const unsigned short* __restrict__ hbuf,   // [NSLOT][H]
                          const unsigned short* __restrict__ wproj,  // [E][D][H]
                          const int* __restrict__ tok_id,
                          const float* __restrict__ tok_w,
                          const int* __restrict__ counts,
                          const int* __restrict__ offsets,
                          float* __restrict__ out) {                 // [N_TOK][D]
  const int e = blockIdx.z >> 1;
  const int kbase = (blockIdx.z & 1) * (H_DIM / 2);
  const int cnt = counts[e];
  const int mtile = blockIdx.x;   // x = mtile: XCD locality for A (hbuf) panels
  if (mtile * 128 >= cnt) return;
  const int ntile = blockIdx.y;   // 0..7 (D=1024)
  const int off = offsets[e];

  __shared__ __align__(16) unsigned short lds[RING * BUFSZ];  // 64 KB

  const int t = threadIdx.x;
  const int lane = t & 63;
  const int wave = t >> 6;
  const int wm = (wave >> 1) * 64;
  const int wn = (wave & 1) * 64;

  const int s0 = t, s1 = t + 256;
  int r0 = mtile * 128 + (s0 >> 2); r0 = (r0 < cnt) ? r0 : (cnt - 1);
  int r1 = mtile * 128 + (s1 >> 2); r1 = (r1 < cnt) ? r1 : (cnt - 1);
  const unsigned short* ga0 = hbuf + (size_t)(off + r0) * H_DIM + kbase + SRC_CHUNK(s0);
  const unsigned short* ga1 = hbuf + (size_t)(off + r1) * H_DIM + kbase + SRC_CHUNK(s1);
  const unsigned short* gb0 = wproj + ((size_t)e * D_DIM + ntile * 128 + (s0 >> 2)) * H_DIM + kbase + SRC_CHUNK(s0);
  const unsigned short* gb1 = wproj + ((size_t)e * D_DIM + ntile * 128 + (s1 >> 2)) * H_DIM + kbase + SRC_CHUNK(s1);

  f32x4 acc[4][4];
#pragma unroll
  for (int i = 0; i < 4; ++i)
#pragma unroll
    for (int j = 0; j < 4; ++j) acc[i][j] = (f32x4){0.f, 0.f, 0.f, 0.f};

  const int fr = lane & 15;
  const int q = lane >> 4;
  const int ch = (q ^ ((fr >> 1) & 3)) * 8;

  const int NK = (H_DIM / 2) / BK;  // 64

#pragma unroll
  for (int p = 0; p < 3; ++p) {
    gld_lds16(ga0 + p * BK, &lds[p * BUFSZ + t * 8]);
    gld_lds16(ga1 + p * BK, &lds[p * BUFSZ + 2048 + t * 8]);
    gld_lds16(gb0 + p * BK, &lds[p * BUFSZ + 4096 + t * 8]);
    gld_lds16(gb1 + p * BK, &lds[p * BUFSZ + 4096 + 2048 + t * 8]);
  }
  asm volatile("s_waitcnt vmcnt(8)" ::: "memory");
  __builtin_amdgcn_s_barrier();

  for (int kt = 0; kt < NK; ++kt) {
    const int bb = (kt & 3) * BUFSZ;
    const unsigned short* Ab = &lds[bb + (wm + fr) * 32 + ch];
    const unsigned short* Bb = &lds[bb + 4096 + (wn + fr) * 32 + ch];

    bf16x8 a_[4], b_[4];
#pragma unroll
    for (int i = 0; i < 4; ++i) a_[i] = *(const bf16x8*)(Ab + i * 512);
#pragma unroll
    for (int j = 0; j < 4; ++j) b_[j] = *(const bf16x8*)(Bb + j * 512);

    if (kt + 3 < NK) {
      const int kof = (kt + 3) * BK;
      const int sb = ((kt + 3) & 3) * BUFSZ;
      gld_lds16(ga0 + kof, &lds[sb + t * 8]);
      gld_lds16(ga1 + kof, &lds[sb + 2048 + t * 8]);
      gld_lds16(gb0 + kof, &lds[sb + 4096 + t * 8]);
      gld_lds16(gb1 + kof, &lds[sb + 4096 + 2048 + t * 8]);
    }

    __builtin_amdgcn_s_setprio(1);
#pragma unroll
    for (int i = 0; i < 4; ++i)
#pragma unroll
      for (int j = 0; j < 4; ++j)
        acc[i][j] = __builtin_amdgcn_mfma_f32_16x16x32_bf16(a_[i], b_[j], acc[i][j], 0, 0, 0);
    __builtin_amdgcn_s_setprio(0);

    if (kt < NK - 3)       asm volatile("s_waitcnt vmcnt(8)" ::: "memory");
    else if (kt == NK - 3) asm volatile("s_waitcnt vmcnt(4)" ::: "memory");
    else if (kt == NK - 2) asm volatile("s_waitcnt vmcnt(0)" ::: "memory");
    if (kt != NK - 1) __builtin_amdgcn_s_barrier();
  }

  // epilogue: scale by routing weight, scatter-add into out
  const int lm = (lane >> 4) * 4;
  const int ln = lane & 15;
#pragma unroll
  for (int i = 0; i < 4; ++i) {
#pragma unroll
    for (int r = 0; r < 4; ++r) {
      int m = mtile * 128 + wm + i * 16 + lm + r;
      if (m < cnt) {
        int slot = off + m;
        float w = tok_w[slot];
        float* orow = out + (size_t)tok_id[slot] * D_DIM + ntile * 128 + wn;
#pragma unroll
        for (int j = 0; j < 4; ++j)
          atomicAdd(&orow[j * 16 + ln], acc[i][j][r] * w);
      }
    }
  }
}

// ---------------- launch ----------------
// ws layout (bytes):
//   0        counts[8] | 64 cursor[8] | 128 offsets[8]
//   256      eidx[4096] | 16640 rw[8192] | 49408 tok_id[8192] | 82176 tok_w[8192]
//   114944   probs[4096*8]         (131072)
//   246016   x_bf16                (8388608)
//   8634624  wfc_bf16              (67108864)
//   75743488 wproj_bf16            (67108864)
//   142852352 hbuf                 (67108864)

extern "C" void kernel_launch(void* const* d_in, const int* in_sizes, int n_in,
                              void* d_out, int out_size, void* d_ws, size_t ws_size,
                              hipStream_t stream) {
  (void)in_sizes; (void)n_in; (void)out_size; (void)ws_size;
  const float* x = (const float*)d_in[0];
  const float* wg = (const float*)d_in[1];
  const float* wfc = (const float*)d_in[2];
  const float* wproj = (const float*)d_in[3];
  float* out = (float*)d_out;
  char* ws = (char*)d_ws;

  int* counts = (int*)(ws + 0);
  int* cursor = (int*)(ws + 64);
  int* offsets = (int*)(ws + 128);
  int* eidx = (int*)(ws + 256);
  float* rw = (float*)(ws + 16640);
  int* tok_id = (int*)(ws + 49408);
  float* tok_w = (float*)(ws + 82176);
  float* probs = (float*)(ws + 114944);
  unsigned short* xb = (unsigned short*)(ws + 246016);
  unsigned short* wfcb = (unsigned short*)(ws + 8634624);
  unsigned short* wpjb = (unsigned short*)(ws + 75743488);
  unsigned short* hbuf = (unsigned short*)(ws + 142852352);

  hipLaunchKernelGGL(init_ctrl, dim3(1), dim3(64), 0, stream, (int*)ws);
  hipLaunchKernelGGL(cvt_f32_bf16, dim3(32768), dim3(256), 0, stream, wfc, wfcb, 8388608);
  hipLaunchKernelGGL(cvt_f32_bf16, dim3(32768), dim3(256), 0, stream, wproj, wpjb, 8388608);
  hipLaunchKernelGGL(cvt_f32_bf16, dim3(4096), dim3(256), 0, stream, x, xb, 1048576);
  hipLaunchKernelGGL(zero_f32, dim3(4096), dim3(256), 0, stream, out, 1048576);
  hipLaunchKernelGGL(gating_kernel, dim3(256), dim3(256), 0, stream, x, wg, probs, eidx, rw);
  hipLaunchKernelGGL(reduce_route, dim3(1), dim3(256), 0, stream, probs, eidx, counts, offsets, out + 4194304);
  hipLaunchKernelGGL(scatter_kernel, dim3(16), dim3(256), 0, stream, eidx, rw, offsets, cursor, tok_id, tok_w);
  // x = mtile (XCD-local A-panels), y = ntile
  hipLaunchKernelGGL(gemm_fc, dim3(32, 32, 8), dim3(256), 0, stream, xb, wfcb, tok_id, counts, offsets, hbuf);
  hipLaunchKernelGGL(gemm_proj, dim3(32, 8, 16), dim3(256), 0, stream, hbuf, wpjb, tok_id, tok_w, counts, offsets, out);
}

// Round 3
// 586.401 us; speedup vs baseline: 1.6700x; 1.6700x over previous
//
#include <hip/hip_runtime.h>
#include <hip/hip_bf16.h>
#include <math.h>

// Problem constants (fixed by reference): B=2,T=2048 -> N=4096 tokens
#define N_TOK 4096
#define D_DIM 1024
#define H_DIM 4096
#define E_NUM 8
#define NSLOT (N_TOK * 2)  // total assignments = N*TOPK = 8192

typedef short bf16x8 __attribute__((ext_vector_type(8)));
typedef float f32x4 __attribute__((ext_vector_type(4)));

// ---------------- helpers ----------------

__device__ __forceinline__ unsigned short f2bf(float f) {
  unsigned int u = __float_as_uint(f);
  u += 0x7FFFu + ((u >> 16) & 1u);  // round-to-nearest-even
  return (unsigned short)(u >> 16);
}

// async global->LDS, 16B per lane. LDS dest is wave-uniform base + lane*16
// (m104: per-lane scatter impossible; hence the XOR *source* swizzle below).
__device__ __forceinline__ void gld_lds16(const void* g, void* l) {
  __builtin_amdgcn_global_load_lds(
      (__attribute__((address_space(1))) void*)(g),
      (__attribute__((address_space(3))) void*)(l), 16, 0, 0);
}

// ---------------- small kernels (fused to cut launch count) ----------------

// zero out[] + control ints (cursor etc.)
__global__ void zero_init(float* __restrict__ p, int n4, int* __restrict__ ctrl) {
  int i = blockIdx.x * blockDim.x + threadIdx.x;
  if (i < n4) ((float4*)p)[i] = make_float4(0.f, 0.f, 0.f, 0.f);
  if (blockIdx.x == 0 && threadIdx.x < 64) ctrl[threadIdx.x] = 0;
}

// both weight matrices in one grid-stride kernel
__global__ void cvt_weights(const float* __restrict__ wfc, const float* __restrict__ wproj,
                            unsigned short* __restrict__ wfcb, unsigned short* __restrict__ wpjb) {
  const int L = 8388608;  // float4s per matrix
  const int stride = gridDim.x * blockDim.x;
  for (int i = blockIdx.x * blockDim.x + threadIdx.x; i < 2 * L; i += stride) {
    const bool first = (i < L);
    const int j = first ? i : i - L;
    float4 v = first ? ((const float4*)wfc)[j] : ((const float4*)wproj)[j];
    ushort4 o;
    o.x = f2bf(v.x); o.y = f2bf(v.y); o.z = f2bf(v.z); o.w = f2bf(v.w);
    if (first) ((ushort4*)wfcb)[j] = o; else ((ushort4*)wpjb)[j] = o;
  }
}

// ---------------- gating: atomic-free; also emits x in bf16 ----------------

__global__ void gating_kernel(const float* __restrict__ x,
                              const float* __restrict__ wg,
                              float* __restrict__ probs,   // [N_TOK][E]
                              int* __restrict__ eidx,
                              float* __restrict__ rw,
                              unsigned short* __restrict__ xb) {  // [N_TOK][D] bf16
  __shared__ float4 wg_lds[2048];  // 8*1024 floats = 32 KB
  const int t = threadIdx.x;
  const int lane = t & 63;
  const int wave = t >> 6;

#pragma unroll
  for (int j = 0; j < 8; ++j)
    wg_lds[t + 256 * j] = ((const float4*)wg)[t + 256 * j];
  __syncthreads();

#pragma unroll
  for (int j = 0; j < 4; ++j) {
    const int n = blockIdx.x * 16 + wave * 4 + j;
    const float4* xr = (const float4*)(x + (size_t)n * D_DIM);
    ushort4* xw = (ushort4*)(xb + (size_t)n * D_DIM);

    float acc[E_NUM];
#pragma unroll
    for (int e = 0; e < E_NUM; ++e) acc[e] = 0.f;

#pragma unroll
    for (int i = 0; i < 4; ++i) {
      float4 xv = xr[lane + 64 * i];
      ushort4 xo;
      xo.x = f2bf(xv.x); xo.y = f2bf(xv.y); xo.z = f2bf(xv.z); xo.w = f2bf(xv.w);
      xw[lane + 64 * i] = xo;
#pragma unroll
      for (int e = 0; e < E_NUM; ++e) {
        float4 wv = wg_lds[e * 256 + lane + 64 * i];
        acc[e] += xv.x * wv.x + xv.y * wv.y + xv.z * wv.z + xv.w * wv.w;
      }
    }
#pragma unroll
    for (int m = 1; m < 64; m <<= 1) {
#pragma unroll
      for (int e = 0; e < E_NUM; ++e) acc[e] += __shfl_xor(acc[e], m, 64);
    }

    float mx = acc[0];
#pragma unroll
    for (int e = 1; e < E_NUM; ++e) mx = fmaxf(mx, acc[e]);
    float p[E_NUM], s = 0.f;
#pragma unroll
    for (int e = 0; e < E_NUM; ++e) { p[e] = __expf(acc[e] - mx); s += p[e]; }
    float inv = 1.f / s;

    if (lane < E_NUM) probs[(size_t)n * E_NUM + lane] = p[lane] * inv;

    if (lane == 0) {
      int i1 = 0;
#pragma unroll
      for (int e = 1; e < E_NUM; ++e) if (p[e] > p[i1]) i1 = e;
      int i2 = (i1 == 0) ? 1 : 0;
#pragma unroll
      for (int e = 0; e < E_NUM; ++e)
        if (e != i1 && p[e] > p[i2]) i2 = e;
      float p1 = p[i1], p2 = p[i2];
      float wsum = 1.f / (p1 + p2);  // top-2 renormalize (softmax scale cancels)
      eidx[n] = i1 | (i2 << 8);
      rw[2 * n] = p1 * wsum;
      rw[2 * n + 1] = p2 * wsum;
    }
  }
}

// single block: sumP column-sums, expert histogram, offsets, balance loss
__global__ void reduce_route(const float* __restrict__ probs,
                             const int* __restrict__ eidx,
                             int* __restrict__ counts,
                             int* __restrict__ offsets,
                             float* __restrict__ loss) {
  const int t = threadIdx.x;
  float4 part = make_float4(0.f, 0.f, 0.f, 0.f);
  for (int j = 0; j < 32; ++j) {
    float4 v = ((const float4*)probs)[t + 256 * j];
    part.x += v.x; part.y += v.y; part.z += v.z; part.w += v.w;
  }
  int cnt[E_NUM];
#pragma unroll
  for (int e = 0; e < E_NUM; ++e) cnt[e] = 0;
  for (int j = 0; j < 16; ++j) {
    int pk = eidx[t + 256 * j];
    int e1 = pk & 255, e2 = pk >> 8;
#pragma unroll
    for (int e = 0; e < E_NUM; ++e) cnt[e] += (e1 == e) + (e2 == e);
  }

  __shared__ float redf[256 * E_NUM];
  __shared__ int redi[256 * E_NUM];
  const int eb = (t & 1) * 4;
#pragma unroll
  for (int e = 0; e < E_NUM; ++e) { redf[t * E_NUM + e] = 0.f; redi[t * E_NUM + e] = cnt[e]; }
  redf[t * E_NUM + eb + 0] = part.x;
  redf[t * E_NUM + eb + 1] = part.y;
  redf[t * E_NUM + eb + 2] = part.z;
  redf[t * E_NUM + eb + 3] = part.w;
  __syncthreads();
  for (int s = 128; s > 0; s >>= 1) {
    if (t < s) {
#pragma unroll
      for (int e = 0; e < E_NUM; ++e) {
        redf[t * E_NUM + e] += redf[(t + s) * E_NUM + e];
        redi[t * E_NUM + e] += redi[(t + s) * E_NUM + e];
      }
    }
    __syncthreads();
  }
  if (t == 0) {
    int o = 0;
    float L = 0.f;
    for (int e = 0; e < E_NUM; ++e) {
      int c = redi[e];
      counts[e] = c;
      offsets[e] = o;
      o += c;
      L += redf[e] * (float)c;
    }
    loss[0] = L * (float)E_NUM / ((float)N_TOK * (float)N_TOK);
  }
}

// two-phase scatter: LDS-local positions, one global atomic per expert/block
__global__ void scatter_kernel(const int* __restrict__ eidx, const float* __restrict__ rw,
                               const int* __restrict__ offsets, int* __restrict__ cursor,
                               int* __restrict__ tok_id, float* __restrict__ tok_w) {
  __shared__ int lcnt[E_NUM];
  __shared__ int lbase[E_NUM];
  const int t = threadIdx.x;
  const int n = blockIdx.x * 256 + t;
  if (t < E_NUM) lcnt[t] = 0;
  __syncthreads();
  int pk = eidx[n];
  int e1 = pk & 255, e2 = pk >> 8;
  int p1 = atomicAdd(&lcnt[e1], 1);
  int p2 = atomicAdd(&lcnt[e2], 1);
  __syncthreads();
  if (t < E_NUM) lbase[t] = atomicAdd(&cursor[t], lcnt[t]);
  __syncthreads();
  int d1 = offsets[e1] + lbase[e1] + p1;
  tok_id[d1] = n; tok_w[d1] = rw[2 * n];
  int d2 = offsets[e2] + lbase[e2] + p2;
  tok_id[d2] = n; tok_w[d2] = rw[2 * n + 1];
}

// ---------------- grouped GEMMs (round-0 structure, best measured) --------
// 128x128x64 tile, 4 waves. C[m][n] = sum_k A[m][k]*B[n][k] (both row-major in k).
// LDS bank fix: XOR swizzle on the *source* chunk (global_load_lds dest must
// stay linear); readers use chunk ((kk>>3)+q) ^ (lane&7) -> 2-way max (free).
// Pipelining attempts on this structure measured neutral-to-negative (R1/R2,
// matching learn_hip m99-m141 nulls) -- keep the simple 2-barrier loop.

__launch_bounds__(256, 2)
__global__ void gemm_fc(const unsigned short* __restrict__ xb,    // [N_TOK][D]
                        const unsigned short* __restrict__ wfc,   // [E][H][D]
                        const int* __restrict__ tok_id,
                        const int* __restrict__ counts,
                        const int* __restrict__ offsets,
                        unsigned short* __restrict__ hbuf) {      // [NSLOT][H]
  const int e = blockIdx.z;
  const int cnt = counts[e];
  const int mtile = blockIdx.y;
  if (mtile * 128 >= cnt) return;
  const int ntile = blockIdx.x;
  const int off = offsets[e];

  __shared__ __align__(16) unsigned short As[128 * 64];
  __shared__ __align__(16) unsigned short Bs[128 * 64];

  const int t = threadIdx.x;
  const int lane = t & 63;
  const int wave = t >> 6;
  const int wm = (wave >> 1) * 64;
  const int wn = (wave & 1) * 64;
  const int srow = t >> 3;                  // LDS row within 32-row plane
  const int seg = (t & 7) ^ (srow & 7);     // XOR-swizzled source chunk

  const unsigned short* aptr[4];
  const unsigned short* bptr[4];
#pragma unroll
  for (int p = 0; p < 4; ++p) {
    int r = mtile * 128 + p * 32 + srow;
    r = (r < cnt) ? r : (cnt - 1);  // clamp: masked at store
    int tok = tok_id[off + r];
    aptr[p] = xb + (size_t)tok * D_DIM + seg * 8;
    int br = ntile * 128 + p * 32 + srow;
    bptr[p] = wfc + ((size_t)e * H_DIM + br) * D_DIM + seg * 8;
  }

  f32x4 acc[4][4];
#pragma unroll
  for (int i = 0; i < 4; ++i)
#pragma unroll
    for (int j = 0; j < 4; ++j) acc[i][j] = (f32x4){0.f, 0.f, 0.f, 0.f};

  const int frow_a = wm + (lane & 15);
  const int frow_b = wn + (lane & 15);
  const int q = lane >> 4;
  const int csw = lane & 7;  // == frow&7 for both A and B (wm,wn mult of 64)

  for (int k0 = 0; k0 < D_DIM; k0 += 64) {
#pragma unroll
    for (int p = 0; p < 4; ++p) {
      gld_lds16(aptr[p] + k0, &As[p * 2048 + t * 8]);
      gld_lds16(bptr[p] + k0, &Bs[p * 2048 + t * 8]);
    }
    __syncthreads();
#pragma unroll
    for (int kk = 0; kk < 64; kk += 32) {
      const int ca = ((((kk >> 3) + q) ^ csw) << 3);
      bf16x8 af[4], bfr[4];
#pragma unroll
      for (int i = 0; i < 4; ++i)
        af[i] = *(const bf16x8*)&As[(frow_a + i * 16) * 64 + ca];
#pragma unroll
      for (int j = 0; j < 4; ++j)
        bfr[j] = *(const bf16x8*)&Bs[(frow_b + j * 16) * 64 + ca];
#pragma unroll
      for (int i = 0; i < 4; ++i)
#pragma unroll
        for (int j = 0; j < 4; ++j)
          acc[i][j] = __builtin_amdgcn_mfma_f32_16x16x32_bf16(af[i], bfr[j], acc[i][j], 0, 0, 0);
    }
    __syncthreads();
  }

  // epilogue: h = relu(t)^2, cast bf16, store
  const int lm = (lane >> 4) * 4;
  const int ln = lane & 15;
#pragma unroll
  for (int i = 0; i < 4; ++i) {
#pragma unroll
    for (int r = 0; r < 4; ++r) {
      int m = mtile * 128 + wm + i * 16 + lm + r;
      if (m < cnt) {
        size_t rowbase = (size_t)(off + m) * H_DIM + ntile * 128 + wn;
#pragma unroll
        for (int j = 0; j < 4; ++j) {
          float v = acc[i][j][r];
          v = v > 0.f ? v * v : 0.f;
          hbuf[rowbase + j * 16 + ln] = f2bf(v);
        }
      }
    }
  }
}

// split-K=4: z = e*4 + kq. R0 proj had only 1024 active blocks (4/CU, occ 24%)
// while fc's 2048 ran faster at identical FLOPs -> machine fill was the proj
// limiter. Split-K=4 doubles proj's active blocks to 2048 (8/CU). All four
// quarters atomicAdd into zero-initialized out.
__launch_bounds__(256, 2)
__global__ void gemm_proj(const unsigned short* __restrict__ hbuf,   // [NSLOT][H]
                          const unsigned short* __restrict__ wproj,  // [E][D][H]
                          const int* __restrict__ tok_id,
                          const float* __restrict__ tok_w,
                          const int* __restrict__ counts,
                          const int* __restrict__ offsets,
                          float* __restrict__ out) {                 // [N_TOK][D]
  const int e = blockIdx.z >> 2;
  const int kbase = (blockIdx.z & 3) * (H_DIM / 4);
  const int cnt = counts[e];
  const int mtile = blockIdx.y;
  if (mtile * 128 >= cnt) return;
  const int ntile = blockIdx.x;  // 0..7 (D=1024)
  const int off = offsets[e];

  __shared__ __align__(16) unsigned short As[128 * 64];
  __shared__ __align__(16) unsigned short Bs[128 * 64];

  const int t = threadIdx.x;
  const int lane = t & 63;
  const int wave = t >> 6;
  const int wm = (wave >> 1) * 64;
  const int wn = (wave & 1) * 64;
  const int srow = t >> 3;
  const int seg = (t & 7) ^ (srow & 7);  // XOR-swizzled source chunk

  const unsigned short* aptr[4];
  const unsigned short* bptr[4];
#pragma unroll
  for (int p = 0; p < 4; ++p) {
    int r = mtile * 128 + p * 32 + srow;
    r = (r < cnt) ? r : (cnt - 1);
    aptr[p] = hbuf + (size_t)(off + r) * H_DIM + seg * 8;
    int br = ntile * 128 + p * 32 + srow;
    bptr[p] = wproj + ((size_t)e * D_DIM + br) * H_DIM + seg * 8;
  }

  f32x4 acc[4][4];
#pragma unroll
  for (int i = 0; i < 4; ++i)
#pragma unroll
    for (int j = 0; j < 4; ++j) acc[i][j] = (f32x4){0.f, 0.f, 0.f, 0.f};

  const int frow_a = wm + (lane & 15);
  const int frow_b = wn + (lane & 15);
  const int q = lane >> 4;
  const int csw = lane & 7;

  for (int k0 = kbase; k0 < kbase + H_DIM / 4; k0 += 64) {
#pragma unroll
    for (int p = 0; p < 4; ++p) {
      gld_lds16(aptr[p] + k0, &As[p * 2048 + t * 8]);
      gld_lds16(bptr[p] + k0, &Bs[p * 2048 + t * 8]);
    }
    __syncthreads();
#pragma unroll
    for (int kk = 0; kk < 64; kk += 32) {
      const int ca = ((((kk >> 3) + q) ^ csw) << 3);
      bf16x8 af[4], bfr[4];
#pragma unroll
      for (int i = 0; i < 4; ++i)
        af[i] = *(const bf16x8*)&As[(frow_a + i * 16) * 64 + ca];
#pragma unroll
      for (int j = 0; j < 4; ++j)
        bfr[j] = *(const bf16x8*)&Bs[(frow_b + j * 16) * 64 + ca];
#pragma unroll
      for (int i = 0; i < 4; ++i)
#pragma unroll
        for (int j = 0; j < 4; ++j)
          acc[i][j] = __builtin_amdgcn_mfma_f32_16x16x32_bf16(af[i], bfr[j], acc[i][j], 0, 0, 0);
    }
    __syncthreads();
  }

  // epilogue: scale by routing weight, scatter-add into out
  const int lm = (lane >> 4) * 4;
  const int ln = lane & 15;
#pragma unroll
  for (int i = 0; i < 4; ++i) {
#pragma unroll
    for (int r = 0; r < 4; ++r) {
      int m = mtile * 128 + wm + i * 16 + lm + r;
      if (m < cnt) {
        int slot = off + m;
        float w = tok_w[slot];
        float* orow = out + (size_t)tok_id[slot] * D_DIM + ntile * 128 + wn;
#pragma unroll
        for (int j = 0; j < 4; ++j)
          atomicAdd(&orow[j * 16 + ln], acc[i][j][r] * w);
      }
    }
  }
}

// ---------------- launch ----------------
// ws layout (bytes):
//   0        counts[8] | 64 cursor[8] | 128 offsets[8]
//   256      eidx[4096] | 16640 rw[8192] | 49408 tok_id[8192] | 82176 tok_w[8192]
//   114944   probs[4096*8]         (131072)
//   246016   x_bf16                (8388608)
//   8634624  wfc_bf16              (67108864)
//   75743488 wproj_bf16            (67108864)
//   142852352 hbuf                 (67108864)

extern "C" void kernel_launch(void* const* d_in, const int* in_sizes, int n_in,
                              void* d_out, int out_size, void* d_ws, size_t ws_size,
                              hipStream_t stream) {
  (void)in_sizes; (void)n_in; (void)out_size; (void)ws_size;
  const float* x = (const float*)d_in[0];
  const float* wg = (const float*)d_in[1];
  const float* wfc = (const float*)d_in[2];
  const float* wproj = (const float*)d_in[3];
  float* out = (float*)d_out;
  char* ws = (char*)d_ws;

  int* counts = (int*)(ws + 0);
  int* cursor = (int*)(ws + 64);
  int* offsets = (int*)(ws + 128);
  int* eidx = (int*)(ws + 256);
  float* rw = (float*)(ws + 16640);
  int* tok_id = (int*)(ws + 49408);
  float* tok_w = (float*)(ws + 82176);
  float* probs = (float*)(ws + 114944);
  unsigned short* xb = (unsigned short*)(ws + 246016);
  unsigned short* wfcb = (unsigned short*)(ws + 8634624);
  unsigned short* wpjb = (unsigned short*)(ws + 75743488);
  unsigned short* hbuf = (unsigned short*)(ws + 142852352);

  hipLaunchKernelGGL(zero_init, dim3(4096), dim3(256), 0, stream, out, 1048576, (int*)ws);
  hipLaunchKernelGGL(cvt_weights, dim3(32768), dim3(256), 0, stream, wfc, wproj, wfcb, wpjb);
  hipLaunchKernelGGL(gating_kernel, dim3(256), dim3(256), 0, stream, x, wg, probs, eidx, rw, xb);
  hipLaunchKernelGGL(reduce_route, dim3(1), dim3(256), 0, stream, probs, eidx, counts, offsets, out + 4194304);
  hipLaunchKernelGGL(scatter_kernel, dim3(16), dim3(256), 0, stream, eidx, rw, offsets, cursor, tok_id, tok_w);
  hipLaunchKernelGGL(gemm_fc, dim3(32, 32, 8), dim3(256), 0, stream, xb, wfcb, tok_id, counts, offsets, hbuf);
  hipLaunchKernelGGL(gemm_proj, dim3(8, 32, 32), dim3(256), 0, stream, hbuf, wpjb, tok_id, tok_w, counts, offsets, out);
}

// Round 4
// 563.444 us; speedup vs baseline: 1.7381x; 1.0407x over previous
//
#include <hip/hip_runtime.h>
#include <hip/hip_bf16.h>
#include <math.h>

// Problem constants (fixed by reference): B=2,T=2048 -> N=4096 tokens
#define N_TOK 4096
#define D_DIM 1024
#define H_DIM 4096
#define E_NUM 8
#define NSLOT (N_TOK * 2)  // total assignments = N*TOPK = 8192

typedef short bf16x8 __attribute__((ext_vector_type(8)));
typedef float f32x4 __attribute__((ext_vector_type(4)));

// ---------------- helpers ----------------

__device__ __forceinline__ unsigned short f2bf(float f) {
  unsigned int u = __float_as_uint(f);
  u += 0x7FFFu + ((u >> 16) & 1u);  // round-to-nearest-even
  return (unsigned short)(u >> 16);
}

// async global->LDS, 16B per lane. LDS dest is wave-uniform base + lane*16
// (m104: per-lane scatter impossible; hence the XOR *source* swizzle below).
__device__ __forceinline__ void gld_lds16(const void* g, void* l) {
  __builtin_amdgcn_global_load_lds(
      (__attribute__((address_space(1))) void*)(g),
      (__attribute__((address_space(3))) void*)(l), 16, 0, 0);
}

// expert offset from counts (8-wide prefix; wave-uniform scalar loads)
__device__ __forceinline__ int expert_off(const int* __restrict__ counts, int e) {
  int o = 0;
  for (int i = 0; i < e; ++i) o += counts[i];
  return o;
}

// ---------------- small kernels (fused to cut launch count) ----------------

// zero out[] + control ints (counts/cursor/sumP)
__global__ void zero_init(float* __restrict__ p, int n4, int* __restrict__ ctrl) {
  int i = blockIdx.x * blockDim.x + threadIdx.x;
  if (i < n4) ((float4*)p)[i] = make_float4(0.f, 0.f, 0.f, 0.f);
  if (blockIdx.x == 0 && threadIdx.x < 64) ctrl[threadIdx.x] = 0;
}

// both weight matrices, grid-stride, 32B loads -> 16B stores per iter
__global__ void cvt_weights(const float* __restrict__ wfc, const float* __restrict__ wproj,
                            unsigned short* __restrict__ wfcb, unsigned short* __restrict__ wpjb) {
  const int U = 4194304;  // ushort8 units per matrix (8*4096*1024 / 8)
  const int stride = gridDim.x * blockDim.x;
  for (int i = blockIdx.x * blockDim.x + threadIdx.x; i < 2 * U; i += stride) {
    const bool first = (i < U);
    const int j = first ? i : i - U;
    const float4* s = ((const float4*)(first ? wfc : wproj)) + 2 * (size_t)j;
    float4 a = s[0], b = s[1];
    bf16x8 o;
    o[0] = (short)f2bf(a.x); o[1] = (short)f2bf(a.y);
    o[2] = (short)f2bf(a.z); o[3] = (short)f2bf(a.w);
    o[4] = (short)f2bf(b.x); o[5] = (short)f2bf(b.y);
    o[6] = (short)f2bf(b.z); o[7] = (short)f2bf(b.w);
    ((bf16x8*)(first ? wfcb : wpjb))[j] = o;
  }
}

// ---------------- gating: atomic-free top2; also emits x bf16, histogram,
// and prob column-sums (for the balance loss) ----------------

__global__ void gating_kernel(const float* __restrict__ x,
                              const float* __restrict__ wg,
                              int* __restrict__ eidx,
                              float* __restrict__ rw,
                              unsigned short* __restrict__ xb,   // [N_TOK][D] bf16
                              int* __restrict__ counts,          // [E] global accum
                              float* __restrict__ sumP) {        // [E] global accum
  __shared__ float4 wg_lds[2048];  // 8*1024 floats = 32 KB
  __shared__ int lhist[E_NUM];
  __shared__ float lsum[E_NUM];
  const int t = threadIdx.x;
  const int lane = t & 63;
  const int wave = t >> 6;

  if (t < E_NUM) { lhist[t] = 0; lsum[t] = 0.f; }
#pragma unroll
  for (int j = 0; j < 8; ++j)
    wg_lds[t + 256 * j] = ((const float4*)wg)[t + 256 * j];
  __syncthreads();

#pragma unroll
  for (int j = 0; j < 4; ++j) {
    const int n = blockIdx.x * 16 + wave * 4 + j;
    const float4* xr = (const float4*)(x + (size_t)n * D_DIM);
    ushort4* xw = (ushort4*)(xb + (size_t)n * D_DIM);

    float acc[E_NUM];
#pragma unroll
    for (int e = 0; e < E_NUM; ++e) acc[e] = 0.f;

#pragma unroll
    for (int i = 0; i < 4; ++i) {
      float4 xv = xr[lane + 64 * i];
      ushort4 xo;
      xo.x = f2bf(xv.x); xo.y = f2bf(xv.y); xo.z = f2bf(xv.z); xo.w = f2bf(xv.w);
      xw[lane + 64 * i] = xo;
#pragma unroll
      for (int e = 0; e < E_NUM; ++e) {
        float4 wv = wg_lds[e * 256 + lane + 64 * i];
        acc[e] += xv.x * wv.x + xv.y * wv.y + xv.z * wv.z + xv.w * wv.w;
      }
    }
#pragma unroll
    for (int m = 1; m < 64; m <<= 1) {
#pragma unroll
      for (int e = 0; e < E_NUM; ++e) acc[e] += __shfl_xor(acc[e], m, 64);
    }

    float mx = acc[0];
#pragma unroll
    for (int e = 1; e < E_NUM; ++e) mx = fmaxf(mx, acc[e]);
    float p[E_NUM], s = 0.f;
#pragma unroll
    for (int e = 0; e < E_NUM; ++e) { p[e] = __expf(acc[e] - mx); s += p[e]; }
    float inv = 1.f / s;

    if (lane < E_NUM) atomicAdd(&lsum[lane], p[lane] * inv);

    if (lane == 0) {
      int i1 = 0;
#pragma unroll
      for (int e = 1; e < E_NUM; ++e) if (p[e] > p[i1]) i1 = e;
      int i2 = (i1 == 0) ? 1 : 0;
#pragma unroll
      for (int e = 0; e < E_NUM; ++e)
        if (e != i1 && p[e] > p[i2]) i2 = e;
      float p1 = p[i1], p2 = p[i2];
      float wsum = 1.f / (p1 + p2);  // top-2 renormalize (softmax scale cancels)
      eidx[n] = i1 | (i2 << 8);
      rw[2 * n] = p1 * wsum;
      rw[2 * n + 1] = p2 * wsum;
      atomicAdd(&lhist[i1], 1);
      atomicAdd(&lhist[i2], 1);
    }
  }
  __syncthreads();
  if (t < E_NUM) {
    atomicAdd(&counts[t], lhist[t]);
    atomicAdd(&sumP[t], lsum[t]);
  }
}

// two-phase scatter: LDS-local positions, one global atomic per expert/block.
// offsets derived from counts in-block; block 0 also emits the balance loss.
__global__ void scatter_kernel(const int* __restrict__ eidx, const float* __restrict__ rw,
                               const int* __restrict__ counts, const float* __restrict__ sumP,
                               int* __restrict__ cursor,
                               int* __restrict__ tok_id, float* __restrict__ tok_w,
                               float* __restrict__ loss) {
  __shared__ int lcnt[E_NUM];
  __shared__ int lbase[E_NUM];
  __shared__ int soff[E_NUM];
  const int t = threadIdx.x;
  const int n = blockIdx.x * 256 + t;
  if (t < E_NUM) {
    lcnt[t] = 0;
    int o = 0;
    for (int i = 0; i < t; ++i) o += counts[i];
    soff[t] = o;
  }
  if (blockIdx.x == 0 && t == 0) {
    float L = 0.f;
    for (int e = 0; e < E_NUM; ++e) L += sumP[e] * (float)counts[e];
    loss[0] = L * (float)E_NUM / ((float)N_TOK * (float)N_TOK);
  }
  __syncthreads();
  int pk = eidx[n];
  int e1 = pk & 255, e2 = pk >> 8;
  int p1 = atomicAdd(&lcnt[e1], 1);
  int p2 = atomicAdd(&lcnt[e2], 1);
  __syncthreads();
  if (t < E_NUM) lbase[t] = atomicAdd(&cursor[t], lcnt[t]);
  __syncthreads();
  int d1 = soff[e1] + lbase[e1] + p1;
  tok_id[d1] = n; tok_w[d1] = rw[2 * n];
  int d2 = soff[e2] + lbase[e2] + p2;
  tok_id[d2] = n; tok_w[d2] = rw[2 * n + 1];
}

// ---------------- grouped GEMMs (round-0 structure, best measured) --------
// 128x128x64 tile, 4 waves. C[m][n] = sum_k A[m][k]*B[n][k] (both row-major in k).
// LDS bank fix: XOR swizzle on the *source* chunk (global_load_lds dest must
// stay linear); readers use chunk ((kk>>3)+q) ^ (lane&7) -> 2-way max (free).
// MEASURED NEGATIVE on this problem (do not retry): ring-buffer counted-vmcnt
// pipelines (R1: 148, R2: 339 vs 137 baseline), split-K=4 (R3: 177 -- atomic
// epilogue doubles and dominates). Keep the simple 2-barrier loop, split-K=2.

__launch_bounds__(256, 2)
__global__ void gemm_fc(const unsigned short* __restrict__ xb,    // [N_TOK][D]
                        const unsigned short* __restrict__ wfc,   // [E][H][D]
                        const int* __restrict__ tok_id,
                        const int* __restrict__ counts,
                        unsigned short* __restrict__ hbuf) {      // [NSLOT][H]
  const int e = blockIdx.z;
  const int cnt = counts[e];
  const int mtile = blockIdx.y;
  if (mtile * 128 >= cnt) return;
  const int ntile = blockIdx.x;
  const int off = expert_off(counts, e);

  __shared__ __align__(16) unsigned short As[128 * 64];
  __shared__ __align__(16) unsigned short Bs[128 * 64];

  const int t = threadIdx.x;
  const int lane = t & 63;
  const int wave = t >> 6;
  const int wm = (wave >> 1) * 64;
  const int wn = (wave & 1) * 64;
  const int srow = t >> 3;                  // LDS row within 32-row plane
  const int seg = (t & 7) ^ (srow & 7);     // XOR-swizzled source chunk

  const unsigned short* aptr[4];
  const unsigned short* bptr[4];
#pragma unroll
  for (int p = 0; p < 4; ++p) {
    int r = mtile * 128 + p * 32 + srow;
    r = (r < cnt) ? r : (cnt - 1);  // clamp: masked at store
    int tok = tok_id[off + r];
    aptr[p] = xb + (size_t)tok * D_DIM + seg * 8;
    int br = ntile * 128 + p * 32 + srow;
    bptr[p] = wfc + ((size_t)e * H_DIM + br) * D_DIM + seg * 8;
  }

  f32x4 acc[4][4];
#pragma unroll
  for (int i = 0; i < 4; ++i)
#pragma unroll
    for (int j = 0; j < 4; ++j) acc[i][j] = (f32x4){0.f, 0.f, 0.f, 0.f};

  const int frow_a = wm + (lane & 15);
  const int frow_b = wn + (lane & 15);
  const int q = lane >> 4;
  const int csw = lane & 7;  // == frow&7 for both A and B (wm,wn mult of 64)

  for (int k0 = 0; k0 < D_DIM; k0 += 64) {
#pragma unroll
    for (int p = 0; p < 4; ++p) {
      gld_lds16(aptr[p] + k0, &As[p * 2048 + t * 8]);
      gld_lds16(bptr[p] + k0, &Bs[p * 2048 + t * 8]);
    }
    __syncthreads();
#pragma unroll
    for (int kk = 0; kk < 64; kk += 32) {
      const int ca = ((((kk >> 3) + q) ^ csw) << 3);
      bf16x8 af[4], bfr[4];
#pragma unroll
      for (int i = 0; i < 4; ++i)
        af[i] = *(const bf16x8*)&As[(frow_a + i * 16) * 64 + ca];
#pragma unroll
      for (int j = 0; j < 4; ++j)
        bfr[j] = *(const bf16x8*)&Bs[(frow_b + j * 16) * 64 + ca];
#pragma unroll
      for (int i = 0; i < 4; ++i)
#pragma unroll
        for (int j = 0; j < 4; ++j)
          acc[i][j] = __builtin_amdgcn_mfma_f32_16x16x32_bf16(af[i], bfr[j], acc[i][j], 0, 0, 0);
    }
    __syncthreads();
  }

  // epilogue: h = relu(t)^2, cast bf16, store
  const int lm = (lane >> 4) * 4;
  const int ln = lane & 15;
#pragma unroll
  for (int i = 0; i < 4; ++i) {
#pragma unroll
    for (int r = 0; r < 4; ++r) {
      int m = mtile * 128 + wm + i * 16 + lm + r;
      if (m < cnt) {
        size_t rowbase = (size_t)(off + m) * H_DIM + ntile * 128 + wn;
#pragma unroll
        for (int j = 0; j < 4; ++j) {
          float v = acc[i][j][r];
          v = v > 0.f ? v * v : 0.f;
          hbuf[rowbase + j * 16 + ln] = f2bf(v);
        }
      }
    }
  }
}

// split-K=2: z = e*2 + khalf (measured optimum; K=4 regressed via atomics).
__launch_bounds__(256, 2)
__global__ void gemm_proj(const unsigned short* __restrict__ hbuf,   // [NSLOT][H]
                          const unsigned short* __restrict__ wproj,  // [E][D][H]
                          const int* __restrict__ tok_id,
                          const float* __restrict__ tok_w,
                          const int* __restrict__ counts,
                          float* __restrict__ out) {                 // [N_TOK][D]
  const int e = blockIdx.z >> 1;
  const int kbase = (blockIdx.z & 1) * (H_DIM / 2);
  const int cnt = counts[e];
  const int mtile = blockIdx.y;
  if (mtile * 128 >= cnt) return;
  const int ntile = blockIdx.x;  // 0..7 (D=1024)
  const int off = expert_off(counts, e);

  __shared__ __align__(16) unsigned short As[128 * 64];
  __shared__ __align__(16) unsigned short Bs[128 * 64];

  const int t = threadIdx.x;
  const int lane = t & 63;
  const int wave = t >> 6;
  const int wm = (wave >> 1) * 64;
  const int wn = (wave & 1) * 64;
  const int srow = t >> 3;
  const int seg = (t & 7) ^ (srow & 7);  // XOR-swizzled source chunk

  const unsigned short* aptr[4];
  const unsigned short* bptr[4];
#pragma unroll
  for (int p = 0; p < 4; ++p) {
    int r = mtile * 128 + p * 32 + srow;
    r = (r < cnt) ? r : (cnt - 1);
    aptr[p] = hbuf + (size_t)(off + r) * H_DIM + seg * 8;
    int br = ntile * 128 + p * 32 + srow;
    bptr[p] = wproj + ((size_t)e * D_DIM + br) * H_DIM + seg * 8;
  }

  f32x4 acc[4][4];
#pragma unroll
  for (int i = 0; i < 4; ++i)
#pragma unroll
    for (int j = 0; j < 4; ++j) acc[i][j] = (f32x4){0.f, 0.f, 0.f, 0.f};

  const int frow_a = wm + (lane & 15);
  const int frow_b = wn + (lane & 15);
  const int q = lane >> 4;
  const int csw = lane & 7;

  for (int k0 = kbase; k0 < kbase + H_DIM / 2; k0 += 64) {
#pragma unroll
    for (int p = 0; p < 4; ++p) {
      gld_lds16(aptr[p] + k0, &As[p * 2048 + t * 8]);
      gld_lds16(bptr[p] + k0, &Bs[p * 2048 + t * 8]);
    }
    __syncthreads();
#pragma unroll
    for (int kk = 0; kk < 64; kk += 32) {
      const int ca = ((((kk >> 3) + q) ^ csw) << 3);
      bf16x8 af[4], bfr[4];
#pragma unroll
      for (int i = 0; i < 4; ++i)
        af[i] = *(const bf16x8*)&As[(frow_a + i * 16) * 64 + ca];
#pragma unroll
      for (int j = 0; j < 4; ++j)
        bfr[j] = *(const bf16x8*)&Bs[(frow_b + j * 16) * 64 + ca];
#pragma unroll
      for (int i = 0; i < 4; ++i)
#pragma unroll
        for (int j = 0; j < 4; ++j)
          acc[i][j] = __builtin_amdgcn_mfma_f32_16x16x32_bf16(af[i], bfr[j], acc[i][j], 0, 0, 0);
    }
    __syncthreads();
  }

  // epilogue: scale by routing weight, scatter-add into out
  const int lm = (lane >> 4) * 4;
  const int ln = lane & 15;
#pragma unroll
  for (int i = 0; i < 4; ++i) {
#pragma unroll
    for (int r = 0; r < 4; ++r) {
      int m = mtile * 128 + wm + i * 16 + lm + r;
      if (m < cnt) {
        int slot = off + m;
        float w = tok_w[slot];
        float* orow = out + (size_t)tok_id[slot] * D_DIM + ntile * 128 + wn;
#pragma unroll
        for (int j = 0; j < 4; ++j)
          atomicAdd(&orow[j * 16 + ln], acc[i][j][r] * w);
      }
    }
  }
}

// ---------------- launch ----------------
// ws layout (bytes):
//   0        counts[8] | 64 cursor[8] | 128 (unused) | 192 sumP[8]f32
//   256      eidx[4096] | 16640 rw[8192] | 49408 tok_id[8192] | 82176 tok_w[8192]
//   246016   x_bf16                (8388608)
//   8634624  wfc_bf16              (67108864)
//   75743488 wproj_bf16            (67108864)
//   142852352 hbuf                 (67108864)

extern "C" void kernel_launch(void* const* d_in, const int* in_sizes, int n_in,
                              void* d_out, int out_size, void* d_ws, size_t ws_size,
                              hipStream_t stream) {
  (void)in_sizes; (void)n_in; (void)out_size; (void)ws_size;
  const float* x = (const float*)d_in[0];
  const float* wg = (const float*)d_in[1];
  const float* wfc = (const float*)d_in[2];
  const float* wproj = (const float*)d_in[3];
  float* out = (float*)d_out;
  char* ws = (char*)d_ws;

  int* counts = (int*)(ws + 0);
  int* cursor = (int*)(ws + 64);
  float* sumP = (float*)(ws + 192);
  int* eidx = (int*)(ws + 256);
  float* rw = (float*)(ws + 16640);
  int* tok_id = (int*)(ws + 49408);
  float* tok_w = (float*)(ws + 82176);
  unsigned short* xb = (unsigned short*)(ws + 246016);
  unsigned short* wfcb = (unsigned short*)(ws + 8634624);
  unsigned short* wpjb = (unsigned short*)(ws + 75743488);
  unsigned short* hbuf = (unsigned short*)(ws + 142852352);

  hipLaunchKernelGGL(zero_init, dim3(4096), dim3(256), 0, stream, out, 1048576, (int*)ws);
  hipLaunchKernelGGL(cvt_weights, dim3(4096), dim3(256), 0, stream, wfc, wproj, wfcb, wpjb);
  hipLaunchKernelGGL(gating_kernel, dim3(256), dim3(256), 0, stream, x, wg, eidx, rw, xb, counts, sumP);
  hipLaunchKernelGGL(scatter_kernel, dim3(16), dim3(256), 0, stream, eidx, rw, counts, sumP, cursor, tok_id, tok_w, out + 4194304);
  hipLaunchKernelGGL(gemm_fc, dim3(32, 32, 8), dim3(256), 0, stream, xb, wfcb, tok_id, counts, hbuf);
  hipLaunchKernelGGL(gemm_proj, dim3(8, 32, 16), dim3(256), 0, stream, hbuf, wpjb, tok_id, tok_w, counts, out);
}